// Round 1
// baseline (622.062 us; speedup 1.0000x reference)
//
#include <hip/hip_runtime.h>
#include <stddef.h>

#define B_ 4
#define N_ 2048
#define C_ 512
#define H_ 8
#define D_ 64
#define M_ 4
#define HM_ 32
#define SCALE_ 0.125f

// workspace layout in floats
#define QK_OFF   0                         // 65536  (B*32*512)
#define DOTS_OFF 65536                     // 2*262144 (ksplit halves)
#define AXP_OFF  (65536 + 524288)          // 589824: 8*65536 n-split partials
#define Q_OFF    1114112                   // 8192
#define OV_OFF   1122304                   // 8192
// total = 1130496 floats ~= 4.4 MB

__global__ __launch_bounds__(256) void zero_kernel(float* __restrict__ wsz, float* __restrict__ out) {
    int idx = blockIdx.x * 256 + threadIdx.x;   // 96 blocks -> 24576
    if (idx < 16384) wsz[idx] = 0.f;
    else out[idx - 16384] = 0.f;
}

// q[r=(b,m)][j] = sum_c x[b,m,c] * Wq[c,j]   (atomic over csplit)
__global__ __launch_bounds__(256) void k1a_q(const float* __restrict__ x, const float* __restrict__ Wq,
                                             float* __restrict__ q_ws) {
    __shared__ float W[64][68];
    __shared__ float xr[16][68];
    int t = threadIdx.x;
    int c0 = blockIdx.x * 64, j0 = blockIdx.y * 64;
    #pragma unroll
    for (int i = 0; i < 4; i++) {
        int f = t + i * 256; int cc = f >> 4, j4 = f & 15;
        *(float4*)&W[cc][j4 * 4] = *(const float4*)&Wq[(size_t)(c0 + cc) * 512 + j0 + j4 * 4];
    }
    {
        int r = t >> 4, c4 = t & 15;
        int b = r >> 2, m = r & 3;
        *(float4*)&xr[r][c4 * 4] = *(const float4*)&x[((size_t)(b * N_) + m) * C_ + c0 + c4 * 4];
    }
    __syncthreads();
    int j = t & 63, rg = t >> 6;
    float acc[4] = {0, 0, 0, 0};
    #pragma unroll 16
    for (int cc = 0; cc < 64; cc++) {
        float w = W[cc][j];
        #pragma unroll
        for (int i = 0; i < 4; i++) acc[i] += xr[rg * 4 + i][cc] * w;
    }
    #pragma unroll
    for (int i = 0; i < 4; i++) {
        int r = rg * 4 + i;
        atomicAdd(&q_ws[r * 512 + j0 + j], acc[i]);
    }
}

// qk[(b*32+h*4+m)][c] = SCALE * sum_d q[r][h*64+d] * Wk[c][h*64+d]   (K=64, plain store)
__global__ __launch_bounds__(256) void k1b_qk(const float* __restrict__ Wkv, const float* __restrict__ q_ws,
                                              float* __restrict__ qk_ws) {
    __shared__ float WkT[64][68];  // [d][cc]
    __shared__ float qh[16][68];   // [r][d]
    int t = threadIdx.x;
    int c0 = blockIdx.x * 64; int h = blockIdx.y;
    #pragma unroll
    for (int i = 0; i < 4; i++) {
        int f = t + i * 256; int cc = f >> 4, d4 = f & 15;
        float4 v = *(const float4*)&Wkv[(size_t)(c0 + cc) * 1024 + h * 64 + d4 * 4];
        WkT[d4 * 4 + 0][cc] = v.x; WkT[d4 * 4 + 1][cc] = v.y;
        WkT[d4 * 4 + 2][cc] = v.z; WkT[d4 * 4 + 3][cc] = v.w;
    }
    {
        int r = t >> 4, d4 = t & 15;
        *(float4*)&qh[r][d4 * 4] = *(const float4*)&q_ws[r * 512 + h * 64 + d4 * 4];
    }
    __syncthreads();
    int c = t & 63, rg = t >> 6;
    float acc[4] = {0, 0, 0, 0};
    #pragma unroll 16
    for (int d = 0; d < 64; d++) {
        float w = WkT[d][c];
        #pragma unroll
        for (int i = 0; i < 4; i++) acc[i] += qh[rg * 4 + i][d] * w;
    }
    #pragma unroll
    for (int i = 0; i < 4; i++) {
        int r = rg * 4 + i; int b = r >> 2, m = r & 3;
        qk_ws[((size_t)(b * HM_) + h * M_ + m) * 512 + c0 + c] = acc[i] * SCALE_;
    }
}

// dots_ks[(b*32+hm)][n] = sum_{c in ksplit half} qk[b,hm,c] * x[b,n,c]
__global__ __launch_bounds__(256) void k2_dots(const float* __restrict__ x, const float* __restrict__ qk_ws,
                                               float* __restrict__ dots) {
    __shared__ float xt[64][66];  // [kk][n]
    __shared__ float qT[64][36];  // [kk][hm]
    int t = threadIdx.x;
    int n0 = blockIdx.x * 64; int b = blockIdx.y; int ks = blockIdx.z;
    int p = t & 31, qg = t >> 5;
    float acc[2][4] = {{0, 0, 0, 0}, {0, 0, 0, 0}};
    for (int ch = 0; ch < 4; ch++) {
        int c0 = ks * 256 + ch * 64;
        #pragma unroll
        for (int i = 0; i < 4; i++) {
            int f = t + i * 256; int n = f >> 4, c4 = f & 15;
            float4 v = *(const float4*)&x[((size_t)(b * N_) + n0 + n) * C_ + c0 + c4 * 4];
            xt[c4 * 4 + 0][n] = v.x; xt[c4 * 4 + 1][n] = v.y;
            xt[c4 * 4 + 2][n] = v.z; xt[c4 * 4 + 3][n] = v.w;
        }
        #pragma unroll
        for (int i = 0; i < 2; i++) {
            int f = t + i * 256; int hm = f >> 4, c4 = f & 15;
            float4 v = *(const float4*)&qk_ws[((size_t)(b * HM_) + hm) * 512 + c0 + c4 * 4];
            qT[c4 * 4 + 0][hm] = v.x; qT[c4 * 4 + 1][hm] = v.y;
            qT[c4 * 4 + 2][hm] = v.z; qT[c4 * 4 + 3][hm] = v.w;
        }
        __syncthreads();
        #pragma unroll 16
        for (int kk = 0; kk < 64; kk++) {
            float2 xv = *(const float2*)&xt[kk][p * 2];
            float4 qv = *(const float4*)&qT[kk][qg * 4];
            acc[0][0] += qv.x * xv.x; acc[1][0] += qv.x * xv.y;
            acc[0][1] += qv.y * xv.x; acc[1][1] += qv.y * xv.y;
            acc[0][2] += qv.z * xv.x; acc[1][2] += qv.z * xv.y;
            acc[0][3] += qv.w * xv.x; acc[1][3] += qv.w * xv.y;
        }
        __syncthreads();
    }
    #pragma unroll
    for (int i = 0; i < 4; i++) {
        int hm = qg * 4 + i;
        *(float2*)&dots[(size_t)ks * 262144 + ((size_t)(b * HM_) + hm) * N_ + n0 + p * 2] =
            make_float2(acc[0][i], acc[1][i]);
    }
}

// softmax((dotsA+dotsB) + bias[b,h,m,:]) -> write attn into dotsA region
__global__ __launch_bounds__(256) void k3_softmax(const float* __restrict__ bias, float* __restrict__ dots) {
    __shared__ float red[256];
    int t = threadIdx.x;
    int row = blockIdx.x;  // b*32+hm
    int b = row >> 5, hm = row & 31, h = hm >> 2, m = hm & 3;
    const float* dA = dots + (size_t)row * N_;
    const float* dB = dots + 262144 + (size_t)row * N_;
    const float* brow = bias + ((size_t)(b * H_ + h) * N_ + m) * N_;
    float v[8];
    float mx = -1e30f;
    #pragma unroll
    for (int i = 0; i < 8; i++) {
        int n = t + i * 256;
        v[i] = dA[n] + dB[n] + brow[n];
        mx = fmaxf(mx, v[i]);
    }
    red[t] = mx; __syncthreads();
    for (int s = 128; s > 0; s >>= 1) { if (t < s) red[t] = fmaxf(red[t], red[t + s]); __syncthreads(); }
    mx = red[0]; __syncthreads();
    float ssum = 0.f;
    #pragma unroll
    for (int i = 0; i < 8; i++) { v[i] = __expf(v[i] - mx); ssum += v[i]; }
    red[t] = ssum; __syncthreads();
    for (int s = 128; s > 0; s >>= 1) { if (t < s) red[t] += red[t + s]; __syncthreads(); }
    float inv = 1.0f / red[0];
    float* aw = dots + (size_t)row * N_;
    #pragma unroll
    for (int i = 0; i < 8; i++) aw[t + i * 256] = v[i] * inv;
}

// axp[(s*B+b)*32+hm][c] = sum_{n in s-chunk} attn[b,hm,n] * x[b,n,c]
__global__ __launch_bounds__(256) void k4_attnx(const float* __restrict__ x, const float* __restrict__ attn,
                                                float* __restrict__ axp) {
    __shared__ float xn[64][68];  // [nn][cc]
    __shared__ float at[64][36];  // [nn][hm]
    int t = threadIdx.x;
    int c0 = blockIdx.x * 64; int s = blockIdx.y; int b = blockIdx.z;
    int p = t & 31, qg = t >> 5;
    float acc[2][4] = {{0, 0, 0, 0}, {0, 0, 0, 0}};
    for (int sub = 0; sub < 4; sub++) {
        int n0 = s * 256 + sub * 64;
        #pragma unroll
        for (int i = 0; i < 4; i++) {
            int f = t + i * 256; int nn = f >> 4, c4 = f & 15;
            *(float4*)&xn[nn][c4 * 4] =
                *(const float4*)&x[((size_t)(b * N_) + n0 + nn) * C_ + c0 + c4 * 4];
        }
        #pragma unroll
        for (int i = 0; i < 2; i++) {
            int f = t + i * 256; int hm = f >> 4, n4 = f & 15;
            float4 v = *(const float4*)&attn[((size_t)(b * HM_) + hm) * N_ + n0 + n4 * 4];
            at[n4 * 4 + 0][hm] = v.x; at[n4 * 4 + 1][hm] = v.y;
            at[n4 * 4 + 2][hm] = v.z; at[n4 * 4 + 3][hm] = v.w;
        }
        __syncthreads();
        #pragma unroll 16
        for (int nn = 0; nn < 64; nn++) {
            float2 xv = *(const float2*)&xn[nn][p * 2];
            float4 av = *(const float4*)&at[nn][qg * 4];
            acc[0][0] += av.x * xv.x; acc[1][0] += av.x * xv.y;
            acc[0][1] += av.y * xv.x; acc[1][1] += av.y * xv.y;
            acc[0][2] += av.z * xv.x; acc[1][2] += av.z * xv.y;
            acc[0][3] += av.w * xv.x; acc[1][3] += av.w * xv.y;
        }
        __syncthreads();
    }
    #pragma unroll
    for (int i = 0; i < 4; i++) {
        int hm = qg * 4 + i;
        *(float2*)&axp[(((size_t)(s * B_) + b) * HM_ + hm) * C_ + c0 + p * 2] =
            make_float2(acc[0][i], acc[1][i]);
    }
}

// ov[r][h*64+e] += sum_{c in csplit} (sum_s axp)[b,h,m,c] * Wv[c][h*64+e]
__global__ __launch_bounds__(256) void k5a_ov(const float* __restrict__ Wkv, const float* __restrict__ axp,
                                              float* __restrict__ ov_ws) {
    __shared__ float Wv[64][68];   // [cc][e]
    __shared__ float axh[16][68];  // [r][cc]
    int t = threadIdx.x;
    int c0 = blockIdx.x * 64; int h = blockIdx.y;
    #pragma unroll
    for (int i = 0; i < 4; i++) {
        int f = t + i * 256; int cc = f >> 4, e4 = f & 15;
        *(float4*)&Wv[cc][e4 * 4] =
            *(const float4*)&Wkv[(size_t)(c0 + cc) * 1024 + 512 + h * 64 + e4 * 4];
    }
    {
        int r = t >> 4, c4 = t & 15;
        int b = r >> 2, m = r & 3;
        float4 a = make_float4(0, 0, 0, 0);
        #pragma unroll
        for (int s = 0; s < 8; s++) {
            float4 v = *(const float4*)&axp[(((size_t)(s * B_) + b) * HM_ + h * M_ + m) * C_ + c0 + c4 * 4];
            a.x += v.x; a.y += v.y; a.z += v.z; a.w += v.w;
        }
        *(float4*)&axh[r][c4 * 4] = a;
    }
    __syncthreads();
    int e = t & 63, rg = t >> 6;
    float acc[4] = {0, 0, 0, 0};
    #pragma unroll 16
    for (int cc = 0; cc < 64; cc++) {
        float w = Wv[cc][e];
        #pragma unroll
        for (int i = 0; i < 4; i++) acc[i] += axh[rg * 4 + i][cc] * w;
    }
    #pragma unroll
    for (int i = 0; i < 4; i++) {
        int r = rg * 4 + i;
        atomicAdd(&ov_ws[r * 512 + h * 64 + e], acc[i]);
    }
}

// out[r][j] += (is==0 ? bo[j] : 0) + sum_{i in isplit} ov[r][i] * Wo[i][j]
__global__ __launch_bounds__(256) void k5b_out(const float* __restrict__ Wo, const float* __restrict__ bo,
                                               const float* __restrict__ ov_ws, float* __restrict__ out) {
    __shared__ float W[64][68];
    __shared__ float ovr[16][68];
    int t = threadIdx.x;
    int i0 = blockIdx.x * 64; int j0 = blockIdx.y * 64;
    #pragma unroll
    for (int i = 0; i < 4; i++) {
        int f = t + i * 256; int ii = f >> 4, j4 = f & 15;
        *(float4*)&W[ii][j4 * 4] = *(const float4*)&Wo[(size_t)(i0 + ii) * 512 + j0 + j4 * 4];
    }
    {
        int r = t >> 4, c4 = t & 15;
        *(float4*)&ovr[r][c4 * 4] = *(const float4*)&ov_ws[r * 512 + i0 + c4 * 4];
    }
    __syncthreads();
    int j = t & 63, rg = t >> 6;
    float binit = (blockIdx.x == 0) ? bo[j0 + j] : 0.f;
    float acc[4] = {binit, binit, binit, binit};
    #pragma unroll 16
    for (int ii = 0; ii < 64; ii++) {
        float w = W[ii][j];
        #pragma unroll
        for (int i = 0; i < 4; i++) acc[i] += ovr[rg * 4 + i][ii] * w;
    }
    #pragma unroll
    for (int i = 0; i < 4; i++) {
        int r = rg * 4 + i;
        atomicAdd(&out[r * 512 + j0 + j], acc[i]);
    }
}

extern "C" void kernel_launch(void* const* d_in, const int* in_sizes, int n_in,
                              void* d_out, int out_size, void* d_ws, size_t ws_size,
                              hipStream_t stream) {
    const float* x    = (const float*)d_in[0];
    const float* bias = (const float*)d_in[1];
    const float* Wq   = (const float*)d_in[2];
    const float* Wkv  = (const float*)d_in[3];
    const float* Wo   = (const float*)d_in[4];
    const float* bo   = (const float*)d_in[5];
    float* out = (float*)d_out;
    float* ws  = (float*)d_ws;

    float* qk_ws = ws + QK_OFF;
    float* dots  = ws + DOTS_OFF;
    float* axp   = ws + AXP_OFF;
    float* q_ws  = ws + Q_OFF;
    float* ov_ws = ws + OV_OFF;

    zero_kernel<<<96, 256, 0, stream>>>(q_ws, out);                 // zeroes q_ws+ov_ws (contig) and out
    k1a_q<<<dim3(8, 8), 256, 0, stream>>>(x, Wq, q_ws);
    k1b_qk<<<dim3(8, 8), 256, 0, stream>>>(Wkv, q_ws, qk_ws);
    k2_dots<<<dim3(32, 4, 2), 256, 0, stream>>>(x, qk_ws, dots);
    k3_softmax<<<128, 256, 0, stream>>>(bias, dots);
    k4_attnx<<<dim3(8, 8, 4), 256, 0, stream>>>(x, dots, axp);
    k5a_ov<<<dim3(8, 8), 256, 0, stream>>>(Wkv, axp, ov_ws);
    k5b_out<<<dim3(8, 8), 256, 0, stream>>>(Wo, bo, ov_ws, out);
}

// Round 2
// 615.771 us; speedup vs baseline: 1.0102x; 1.0102x over previous
//
#include <hip/hip_runtime.h>
#include <stddef.h>

#define B_ 4
#define N_ 2048
#define C_ 512
#define H_ 8
#define D_ 64
#define M_ 4
#define HM_ 32
#define SCALE_ 0.125f

// workspace layout in floats
#define QK_OFF   0                         // 65536  (B*32*512)
#define DOTS_OFF 65536                     // 4*262144 (ksplit quarters)
#define AXP_OFF  (65536 + 1048576)         // 16*4*32*512 = 1048576 s-split partials
#define Q_OFF    (65536 + 1048576 + 1048576)   // 8192
#define OV_OFF   (Q_OFF + 8192)                // 8192
// total ~= 8.5 MB

__global__ __launch_bounds__(256) void zero_kernel(float* __restrict__ wsz, float* __restrict__ out) {
    int idx = blockIdx.x * 256 + threadIdx.x;   // 96 blocks -> 24576
    if (idx < 16384) wsz[idx] = 0.f;
    else out[idx - 16384] = 0.f;
}

// q[r=(b,m)][j] = sum_c x[b,m,c] * Wq[c,j]   (atomic over csplit)
__global__ __launch_bounds__(256) void k1a_q(const float* __restrict__ x, const float* __restrict__ Wq,
                                             float* __restrict__ q_ws) {
    __shared__ float W[64][68];
    __shared__ float xr[16][68];
    int t = threadIdx.x;
    int c0 = blockIdx.x * 64, j0 = blockIdx.y * 64;
    #pragma unroll
    for (int i = 0; i < 4; i++) {
        int f = t + i * 256; int cc = f >> 4, j4 = f & 15;
        *(float4*)&W[cc][j4 * 4] = *(const float4*)&Wq[(size_t)(c0 + cc) * 512 + j0 + j4 * 4];
    }
    {
        int r = t >> 4, c4 = t & 15;
        int b = r >> 2, m = r & 3;
        *(float4*)&xr[r][c4 * 4] = *(const float4*)&x[((size_t)(b * N_) + m) * C_ + c0 + c4 * 4];
    }
    __syncthreads();
    int j = t & 63, rg = t >> 6;
    float acc[4] = {0, 0, 0, 0};
    #pragma unroll 16
    for (int cc = 0; cc < 64; cc++) {
        float w = W[cc][j];
        #pragma unroll
        for (int i = 0; i < 4; i++) acc[i] += xr[rg * 4 + i][cc] * w;
    }
    #pragma unroll
    for (int i = 0; i < 4; i++) {
        int r = rg * 4 + i;
        atomicAdd(&q_ws[r * 512 + j0 + j], acc[i]);
    }
}

// qk[(b*32+h*4+m)][c] = SCALE * sum_d q[r][h*64+d] * Wk[c][h*64+d]
__global__ __launch_bounds__(256) void k1b_qk(const float* __restrict__ Wkv, const float* __restrict__ q_ws,
                                              float* __restrict__ qk_ws) {
    __shared__ float WkT[64][68];  // [d][cc]
    __shared__ float qh[16][68];   // [r][d]
    int t = threadIdx.x;
    int c0 = blockIdx.x * 64; int h = blockIdx.y;
    #pragma unroll
    for (int i = 0; i < 4; i++) {
        int f = t + i * 256; int cc = f >> 4, d4 = f & 15;
        float4 v = *(const float4*)&Wkv[(size_t)(c0 + cc) * 1024 + h * 64 + d4 * 4];
        WkT[d4 * 4 + 0][cc] = v.x; WkT[d4 * 4 + 1][cc] = v.y;
        WkT[d4 * 4 + 2][cc] = v.z; WkT[d4 * 4 + 3][cc] = v.w;
    }
    {
        int r = t >> 4, d4 = t & 15;
        *(float4*)&qh[r][d4 * 4] = *(const float4*)&q_ws[r * 512 + h * 64 + d4 * 4];
    }
    __syncthreads();
    int c = t & 63, rg = t >> 6;
    float acc[4] = {0, 0, 0, 0};
    #pragma unroll 16
    for (int d = 0; d < 64; d++) {
        float w = WkT[d][c];
        #pragma unroll
        for (int i = 0; i < 4; i++) acc[i] += qh[rg * 4 + i][d] * w;
    }
    #pragma unroll
    for (int i = 0; i < 4; i++) {
        int r = rg * 4 + i; int b = r >> 2, m = r & 3;
        qk_ws[((size_t)(b * HM_) + h * M_ + m) * 512 + c0 + c] = acc[i] * SCALE_;
    }
}

// dots_ks[(b*32+hm)][n] = sum_{c in ksplit quarter} qk[b,hm,c] * x[b,n,c]
// block: 128 n x 32 hm, lane tile 4hm x 4n. K-chunk = 128 c (2 sub-chunks of 64).
__global__ __launch_bounds__(256) void k2_dots(const float* __restrict__ x, const float* __restrict__ qk_ws,
                                               float* __restrict__ dots) {
    __shared__ __align__(16) float xt[64][132];  // [cc][n_local], dense b128 r/w
    __shared__ __align__(16) float qT[64][36];   // [cc][hm], scatter-write 2-way (free)
    int t = threadIdx.x;
    int n0 = blockIdx.x * 128; int b = blockIdx.y; int ks = blockIdx.z;
    int p = t & 31, g = t >> 5;
    float acc[4][4] = {{0,0,0,0},{0,0,0,0},{0,0,0,0},{0,0,0,0}};
    for (int ch = 0; ch < 2; ch++) {
        int cs = ks * 128 + ch * 64;
        // x^T staging: per-lane 4 strided global b32 loads (64B-segment coalesced),
        // one dense b128 LDS write per iter (no transpose scatter).
        #pragma unroll
        for (int it = 0; it < 8; it++) {
            int cc = (t & 15) + 16 * (it & 3);
            int q  = (t >> 4) + 16 * (it >> 2);
            const float* gp = &x[((size_t)(b * N_) + n0 + 4 * q) * C_ + cs + cc];
            float4 v;
            v.x = gp[0]; v.y = gp[C_]; v.z = gp[2 * C_]; v.w = gp[3 * C_];
            *(float4*)&xt[cc][4 * q] = v;
        }
        #pragma unroll
        for (int i = 0; i < 2; i++) {
            int f = t + i * 256; int hm = f >> 4, c4 = f & 15;
            float4 v = *(const float4*)&qk_ws[((size_t)(b * HM_) + hm) * 512 + cs + c4 * 4];
            qT[c4 * 4 + 0][hm] = v.x; qT[c4 * 4 + 1][hm] = v.y;
            qT[c4 * 4 + 2][hm] = v.z; qT[c4 * 4 + 3][hm] = v.w;
        }
        __syncthreads();
        #pragma unroll 8
        for (int kk = 0; kk < 64; kk++) {
            float4 xv = *(const float4*)&xt[kk][p * 4];
            float4 qv = *(const float4*)&qT[kk][g * 4];
            acc[0][0] += qv.x * xv.x; acc[0][1] += qv.x * xv.y; acc[0][2] += qv.x * xv.z; acc[0][3] += qv.x * xv.w;
            acc[1][0] += qv.y * xv.x; acc[1][1] += qv.y * xv.y; acc[1][2] += qv.y * xv.z; acc[1][3] += qv.y * xv.w;
            acc[2][0] += qv.z * xv.x; acc[2][1] += qv.z * xv.y; acc[2][2] += qv.z * xv.z; acc[2][3] += qv.z * xv.w;
            acc[3][0] += qv.w * xv.x; acc[3][1] += qv.w * xv.y; acc[3][2] += qv.w * xv.z; acc[3][3] += qv.w * xv.w;
        }
        __syncthreads();
    }
    #pragma unroll
    for (int i = 0; i < 4; i++) {
        int hm = g * 4 + i;
        *(float4*)&dots[(size_t)ks * 262144 + ((size_t)(b * HM_) + hm) * N_ + n0 + p * 4] =
            make_float4(acc[i][0], acc[i][1], acc[i][2], acc[i][3]);
    }
}

// softmax(sum_ks dots_ks + bias[b,h,m,:]) -> write attn into dots[0] region
__global__ __launch_bounds__(256) void k3_softmax(const float* __restrict__ bias, float* __restrict__ dots) {
    __shared__ float red[256];
    int t = threadIdx.x;
    int row = blockIdx.x;  // b*32+hm
    int b = row >> 5, hm = row & 31, h = hm >> 2, m = hm & 3;
    const float* d0 = dots + (size_t)row * N_;
    const float* d1 = dots + 262144 + (size_t)row * N_;
    const float* d2 = dots + 524288 + (size_t)row * N_;
    const float* d3 = dots + 786432 + (size_t)row * N_;
    const float* brow = bias + ((size_t)(b * H_ + h) * N_ + m) * N_;
    float v[8];
    float mx = -1e30f;
    #pragma unroll
    for (int i = 0; i < 8; i++) {
        int n = t + i * 256;
        v[i] = d0[n] + d1[n] + d2[n] + d3[n] + brow[n];
        mx = fmaxf(mx, v[i]);
    }
    red[t] = mx; __syncthreads();
    for (int s = 128; s > 0; s >>= 1) { if (t < s) red[t] = fmaxf(red[t], red[t + s]); __syncthreads(); }
    mx = red[0]; __syncthreads();
    float ssum = 0.f;
    #pragma unroll
    for (int i = 0; i < 8; i++) { v[i] = __expf(v[i] - mx); ssum += v[i]; }
    red[t] = ssum; __syncthreads();
    for (int s = 128; s > 0; s >>= 1) { if (t < s) red[t] += red[t + s]; __syncthreads(); }
    float inv = 1.0f / red[0];
    float* aw = dots + (size_t)row * N_;
    #pragma unroll
    for (int i = 0; i < 8; i++) aw[t + i * 256] = v[i] * inv;
}

// axp[(s*B+b)*32+hm][c] = sum_{n in s-chunk(128)} attn[b,hm,n] * x[b,n,c]
// block: 128 c x 32 hm, lane tile 4hm x 4c.
__global__ __launch_bounds__(256) void k4_attnx(const float* __restrict__ x, const float* __restrict__ attn,
                                                float* __restrict__ axp) {
    __shared__ __align__(16) float xn[64][132];  // [nn][c_local], natural layout (dense)
    __shared__ __align__(16) float at[64][36];   // [nn][hm]
    int t = threadIdx.x;
    int c0 = blockIdx.x * 128; int s = blockIdx.y; int b = blockIdx.z;
    int p = t & 31, g = t >> 5;
    float acc[4][4] = {{0,0,0,0},{0,0,0,0},{0,0,0,0},{0,0,0,0}};
    for (int sub = 0; sub < 2; sub++) {
        int n0 = s * 128 + sub * 64;
        #pragma unroll
        for (int i = 0; i < 8; i++) {
            int f = t + i * 256; int nn = f >> 5, c8 = f & 31;
            *(float4*)&xn[nn][c8 * 4] =
                *(const float4*)&x[((size_t)(b * N_) + n0 + nn) * C_ + c0 + c8 * 4];
        }
        #pragma unroll
        for (int i = 0; i < 2; i++) {
            int f = t + i * 256; int hm = f >> 4, n4 = f & 15;
            float4 v = *(const float4*)&attn[((size_t)(b * HM_) + hm) * N_ + n0 + n4 * 4];
            at[n4 * 4 + 0][hm] = v.x; at[n4 * 4 + 1][hm] = v.y;
            at[n4 * 4 + 2][hm] = v.z; at[n4 * 4 + 3][hm] = v.w;
        }
        __syncthreads();
        #pragma unroll 8
        for (int nn = 0; nn < 64; nn++) {
            float4 xv = *(const float4*)&xn[nn][p * 4];
            float4 av = *(const float4*)&at[nn][g * 4];
            acc[0][0] += av.x * xv.x; acc[0][1] += av.x * xv.y; acc[0][2] += av.x * xv.z; acc[0][3] += av.x * xv.w;
            acc[1][0] += av.y * xv.x; acc[1][1] += av.y * xv.y; acc[1][2] += av.y * xv.z; acc[1][3] += av.y * xv.w;
            acc[2][0] += av.z * xv.x; acc[2][1] += av.z * xv.y; acc[2][2] += av.z * xv.z; acc[2][3] += av.z * xv.w;
            acc[3][0] += av.w * xv.x; acc[3][1] += av.w * xv.y; acc[3][2] += av.w * xv.z; acc[3][3] += av.w * xv.w;
        }
        __syncthreads();
    }
    #pragma unroll
    for (int i = 0; i < 4; i++) {
        int hm = g * 4 + i;
        *(float4*)&axp[(((size_t)(s * B_) + b) * HM_ + hm) * C_ + c0 + p * 4] =
            make_float4(acc[i][0], acc[i][1], acc[i][2], acc[i][3]);
    }
}

// ov[r][h*64+e] += sum_{c in csplit} (sum_s axp)[b,h,m,c] * Wv[c][h*64+e]
__global__ __launch_bounds__(256) void k5a_ov(const float* __restrict__ Wkv, const float* __restrict__ axp,
                                              float* __restrict__ ov_ws) {
    __shared__ float Wv[64][68];   // [cc][e]
    __shared__ float axh[16][68];  // [r][cc]
    int t = threadIdx.x;
    int c0 = blockIdx.x * 64; int h = blockIdx.y;
    #pragma unroll
    for (int i = 0; i < 4; i++) {
        int f = t + i * 256; int cc = f >> 4, e4 = f & 15;
        *(float4*)&Wv[cc][e4 * 4] =
            *(const float4*)&Wkv[(size_t)(c0 + cc) * 1024 + 512 + h * 64 + e4 * 4];
    }
    {
        int r = t >> 4, c4 = t & 15;
        int b = r >> 2, m = r & 3;
        float4 a = make_float4(0, 0, 0, 0);
        #pragma unroll
        for (int s = 0; s < 16; s++) {
            float4 v = *(const float4*)&axp[(((size_t)(s * B_) + b) * HM_ + h * M_ + m) * C_ + c0 + c4 * 4];
            a.x += v.x; a.y += v.y; a.z += v.z; a.w += v.w;
        }
        *(float4*)&axh[r][c4 * 4] = a;
    }
    __syncthreads();
    int e = t & 63, rg = t >> 6;
    float acc[4] = {0, 0, 0, 0};
    #pragma unroll 16
    for (int cc = 0; cc < 64; cc++) {
        float w = Wv[cc][e];
        #pragma unroll
        for (int i = 0; i < 4; i++) acc[i] += axh[rg * 4 + i][cc] * w;
    }
    #pragma unroll
    for (int i = 0; i < 4; i++) {
        int r = rg * 4 + i;
        atomicAdd(&ov_ws[r * 512 + h * 64 + e], acc[i]);
    }
}

// out[r][j] += (is==0 ? bo[j] : 0) + sum_{i in isplit} ov[r][i] * Wo[i][j]
__global__ __launch_bounds__(256) void k5b_out(const float* __restrict__ Wo, const float* __restrict__ bo,
                                               const float* __restrict__ ov_ws, float* __restrict__ out) {
    __shared__ float W[64][68];
    __shared__ float ovr[16][68];
    int t = threadIdx.x;
    int i0 = blockIdx.x * 64; int j0 = blockIdx.y * 64;
    #pragma unroll
    for (int i = 0; i < 4; i++) {
        int f = t + i * 256; int ii = f >> 4, j4 = f & 15;
        *(float4*)&W[ii][j4 * 4] = *(const float4*)&Wo[(size_t)(i0 + ii) * 512 + j0 + j4 * 4];
    }
    {
        int r = t >> 4, c4 = t & 15;
        *(float4*)&ovr[r][c4 * 4] = *(const float4*)&ov_ws[r * 512 + i0 + c4 * 4];
    }
    __syncthreads();
    int j = t & 63, rg = t >> 6;
    float binit = (blockIdx.x == 0) ? bo[j0 + j] : 0.f;
    float acc[4] = {binit, binit, binit, binit};
    #pragma unroll 16
    for (int ii = 0; ii < 64; ii++) {
        float w = W[ii][j];
        #pragma unroll
        for (int i = 0; i < 4; i++) acc[i] += ovr[rg * 4 + i][ii] * w;
    }
    #pragma unroll
    for (int i = 0; i < 4; i++) {
        int r = rg * 4 + i;
        atomicAdd(&out[r * 512 + j0 + j], acc[i]);
    }
}

extern "C" void kernel_launch(void* const* d_in, const int* in_sizes, int n_in,
                              void* d_out, int out_size, void* d_ws, size_t ws_size,
                              hipStream_t stream) {
    const float* x    = (const float*)d_in[0];
    const float* bias = (const float*)d_in[1];
    const float* Wq   = (const float*)d_in[2];
    const float* Wkv  = (const float*)d_in[3];
    const float* Wo   = (const float*)d_in[4];
    const float* bo   = (const float*)d_in[5];
    float* out = (float*)d_out;
    float* ws  = (float*)d_ws;

    float* qk_ws = ws + QK_OFF;
    float* dots  = ws + DOTS_OFF;
    float* axp   = ws + AXP_OFF;
    float* q_ws  = ws + Q_OFF;
    float* ov_ws = ws + OV_OFF;

    zero_kernel<<<96, 256, 0, stream>>>(q_ws, out);                 // zeroes q_ws+ov_ws (contig) and out
    k1a_q<<<dim3(8, 8), 256, 0, stream>>>(x, Wq, q_ws);
    k1b_qk<<<dim3(8, 8), 256, 0, stream>>>(Wkv, q_ws, qk_ws);
    k2_dots<<<dim3(16, 4, 4), 256, 0, stream>>>(x, qk_ws, dots);
    k3_softmax<<<128, 256, 0, stream>>>(bias, dots);
    k4_attnx<<<dim3(4, 16, 4), 256, 0, stream>>>(x, dots, axp);
    k5a_ov<<<dim3(8, 8), 256, 0, stream>>>(Wkv, axp, ov_ws);
    k5b_out<<<dim3(8, 8), 256, 0, stream>>>(Wo, bo, ov_ws, out);
}

// Round 3
// 609.833 us; speedup vs baseline: 1.0201x; 1.0097x over previous
//
#include <hip/hip_runtime.h>
#include <stddef.h>

#define B_ 4
#define N_ 2048
#define C_ 512
#define H_ 8
#define D_ 64
#define M_ 4
#define HM_ 32
#define S_ 64            // n-chunks for flash split (n-chunk = 32)
#define SCALE_ 0.125f

// workspace layout in floats
#define QK_OFF   0                        // 4*32*512      = 65536
#define PAX_OFF  65536                    // 64*4*32*512   = 4194304
#define MLOC_OFF (65536 + 4194304)        // 8192
#define LLOC_OFF (MLOC_OFF + 8192)        // 8192
#define QP_OFF   (LLOC_OFF + 8192)        // 8*16*512      = 65536
#define OVP_OFF  (QP_OFF + 65536)         // 8*16*512      = 65536
// total ~17.6 MB

// q_part[cs][r=(b,m)][j] = sum_{c in cs-chunk} x[b,m,c] * Wq[c,j]   (no atomics)
__global__ __launch_bounds__(256) void k1a_q(const float* __restrict__ x, const float* __restrict__ Wq,
                                             float* __restrict__ q_part) {
    __shared__ float W[64][68];
    __shared__ float xr[16][68];
    int t = threadIdx.x;
    int c0 = blockIdx.x * 64, j0 = blockIdx.y * 64;
    #pragma unroll
    for (int i = 0; i < 4; i++) {
        int f = t + i * 256; int cc = f >> 4, j4 = f & 15;
        *(float4*)&W[cc][j4 * 4] = *(const float4*)&Wq[(size_t)(c0 + cc) * 512 + j0 + j4 * 4];
    }
    {
        int r = t >> 4, c4 = t & 15;
        int b = r >> 2, m = r & 3;
        *(float4*)&xr[r][c4 * 4] = *(const float4*)&x[((size_t)(b * N_) + m) * C_ + c0 + c4 * 4];
    }
    __syncthreads();
    int j = t & 63, rg = t >> 6;
    float acc[4] = {0, 0, 0, 0};
    #pragma unroll 16
    for (int cc = 0; cc < 64; cc++) {
        float w = W[cc][j];
        #pragma unroll
        for (int i = 0; i < 4; i++) acc[i] += xr[rg * 4 + i][cc] * w;
    }
    #pragma unroll
    for (int i = 0; i < 4; i++) {
        int r = rg * 4 + i;
        q_part[((size_t)blockIdx.x * 16 + r) * 512 + j0 + j] = acc[i];
    }
}

// qk[(b*32+h*4+m)][c] = SCALE * sum_d q[r][h*64+d] * Wk[c][h*64+d];  q = sum_cs q_part.
// Also zeroes `out` (needed by k5b atomics).
__global__ __launch_bounds__(256) void k1b_qk(const float* __restrict__ Wkv, const float* __restrict__ q_part,
                                              float* __restrict__ qk_ws, float* __restrict__ out) {
    __shared__ float WkT[64][68];  // [d][cc]
    __shared__ float qh[16][68];   // [r][d]
    int t = threadIdx.x;
    int c0 = blockIdx.x * 64; int h = blockIdx.y;
    int bid = blockIdx.y * 8 + blockIdx.x;
    if (bid < 32) out[bid * 256 + t] = 0.f;   // 32*256 = 8192 = out size
    #pragma unroll
    for (int i = 0; i < 4; i++) {
        int f = t + i * 256; int cc = f >> 4, d4 = f & 15;
        float4 v = *(const float4*)&Wkv[(size_t)(c0 + cc) * 1024 + h * 64 + d4 * 4];
        WkT[d4 * 4 + 0][cc] = v.x; WkT[d4 * 4 + 1][cc] = v.y;
        WkT[d4 * 4 + 2][cc] = v.z; WkT[d4 * 4 + 3][cc] = v.w;
    }
    {
        int r = t >> 4, d4 = t & 15;
        float4 a = make_float4(0.f, 0.f, 0.f, 0.f);
        #pragma unroll
        for (int cs = 0; cs < 8; cs++) {
            float4 v = *(const float4*)&q_part[((size_t)cs * 16 + r) * 512 + h * 64 + d4 * 4];
            a.x += v.x; a.y += v.y; a.z += v.z; a.w += v.w;
        }
        *(float4*)&qh[r][d4 * 4] = a;
    }
    __syncthreads();
    int c = t & 63, rg = t >> 6;
    float acc[4] = {0, 0, 0, 0};
    #pragma unroll 16
    for (int d = 0; d < 64; d++) {
        float w = WkT[d][c];
        #pragma unroll
        for (int i = 0; i < 4; i++) acc[i] += qh[rg * 4 + i][d] * w;
    }
    #pragma unroll
    for (int i = 0; i < 4; i++) {
        int r = rg * 4 + i; int b = r >> 2, m = r & 3;
        qk_ws[((size_t)(b * HM_) + h * M_ + m) * 512 + c0 + c] = acc[i] * SCALE_;
    }
}

// Fused flash chunk: per (s, b): dots(32hm x 32n over K=512) + bias -> local softmax (m,l)
// -> pax[s][b][hm][c] = sum_n exp(dots - m_loc) * x[n][c]   (unnormalized)
__global__ __launch_bounds__(256) void k234_flash(const float* __restrict__ x, const float* __restrict__ qk_ws,
                                                  const float* __restrict__ bias,
                                                  float* __restrict__ pax, float* __restrict__ mloc,
                                                  float* __restrict__ lloc) {
    __shared__ __align__(16) float qk_s[32][516];      // 66 KB, pitch 516 -> conflict-free b128
    __shared__ __align__(16) float scratch[4][32][32]; // 16 KB split-reduce
    __shared__ __align__(16) float dmat[32][36];
    __shared__ __align__(16) float pT[32][36];         // p transposed [n][hm]
    __shared__ float mrow[32];
    __shared__ float red8[32][8];
    int t = threadIdx.x;
    int s = blockIdx.x, b = blockIdx.y;
    int n0 = s * 32;

    // stage qk rows for this b (32 x 512)
    #pragma unroll
    for (int k = 0; k < 16; k++) {
        int idx = t + k * 256;           // 0..4095 float4s
        int row = idx >> 7, c4 = idx & 127;
        *(float4*)&qk_s[row][c4 * 4] =
            *(const float4*)&qk_ws[((size_t)(b * HM_) + row) * 512 + c4 * 4];
    }
    __syncthreads();

    // ---- phase 1: dots. thread tile 8hm x 4n, 8-way c-split ----
    int hmg = t >> 6;            // 0..3 (= wave)
    int ng  = (t >> 3) & 7;      // 0..7
    int cs  = t & 7;             // 0..7
    float d[8][4];
    #pragma unroll
    for (int i = 0; i < 8; i++)
        #pragma unroll
        for (int jn = 0; jn < 4; jn++) d[i][jn] = 0.f;

    const float* xp = &x[((size_t)(b * N_) + n0 + ng * 4) * C_];
    const float* qrow = &qk_s[hmg * 8][0];
    #pragma unroll 2
    for (int step = 0; step < 16; step++) {
        int cbase = cs * 4 + step * 32;
        float4 xv[4];
        #pragma unroll
        for (int jn = 0; jn < 4; jn++)
            xv[jn] = *(const float4*)&xp[(size_t)jn * C_ + cbase];
        #pragma unroll
        for (int i = 0; i < 8; i++) {
            float4 qv = *(const float4*)&qrow[i * 516 + cbase];
            #pragma unroll
            for (int jn = 0; jn < 4; jn++) {
                d[i][jn] += qv.x * xv[jn].x + qv.y * xv[jn].y + qv.z * xv[jn].z + qv.w * xv[jn].w;
            }
        }
    }
    // split-reduce over cs (8 -> 1), 3 rounds
    int pos = hmg * 8 + ng;
    if (cs >= 4) {
        #pragma unroll
        for (int i = 0; i < 8; i++)
            *(float4*)&scratch[cs - 4][pos][i * 4] = make_float4(d[i][0], d[i][1], d[i][2], d[i][3]);
    }
    __syncthreads();
    if (cs < 4) {
        #pragma unroll
        for (int i = 0; i < 8; i++) {
            float4 v = *(float4*)&scratch[cs][pos][i * 4];
            d[i][0] += v.x; d[i][1] += v.y; d[i][2] += v.z; d[i][3] += v.w;
        }
    }
    __syncthreads();
    if (cs == 2 || cs == 3) {
        #pragma unroll
        for (int i = 0; i < 8; i++)
            *(float4*)&scratch[cs - 2][pos][i * 4] = make_float4(d[i][0], d[i][1], d[i][2], d[i][3]);
    }
    __syncthreads();
    if (cs < 2) {
        #pragma unroll
        for (int i = 0; i < 8; i++) {
            float4 v = *(float4*)&scratch[cs][pos][i * 4];
            d[i][0] += v.x; d[i][1] += v.y; d[i][2] += v.z; d[i][3] += v.w;
        }
    }
    __syncthreads();
    if (cs == 1) {
        #pragma unroll
        for (int i = 0; i < 8; i++)
            *(float4*)&scratch[0][pos][i * 4] = make_float4(d[i][0], d[i][1], d[i][2], d[i][3]);
    }
    __syncthreads();
    if (cs == 0) {
        #pragma unroll
        for (int i = 0; i < 8; i++) {
            float4 v = *(float4*)&scratch[0][pos][i * 4];
            *(float4*)&dmat[hmg * 8 + i][ng * 4] =
                make_float4(d[i][0] + v.x, d[i][1] + v.y, d[i][2] + v.z, d[i][3] + v.w);
        }
    }
    __syncthreads();

    // ---- phase 2: bias + local softmax ----
    int row = t >> 3, j = t & 7;   // row = hm, 8 threads/row over 32 n
    int h = row >> 2, m = row & 3;
    float4 dv = *(float4*)&dmat[row][j * 4];
    float4 bv = *(const float4*)&bias[(((size_t)(b * H_) + h) * N_ + m) * N_ + n0 + j * 4];
    float v0 = dv.x + bv.x, v1 = dv.y + bv.y, v2 = dv.z + bv.z, v3 = dv.w + bv.w;
    float pmax = fmaxf(fmaxf(v0, v1), fmaxf(v2, v3));
    red8[row][j] = pmax;
    __syncthreads();
    if (j == 0) {
        float mg = red8[row][0];
        #pragma unroll
        for (int k = 1; k < 8; k++) mg = fmaxf(mg, red8[row][k]);
        mrow[row] = mg;
    }
    __syncthreads();
    float mg = mrow[row];
    float e0 = __expf(v0 - mg), e1 = __expf(v1 - mg), e2 = __expf(v2 - mg), e3 = __expf(v3 - mg);
    red8[row][j] = e0 + e1 + e2 + e3;
    __syncthreads();
    if (j == 0) {
        float ls = red8[row][0];
        #pragma unroll
        for (int k = 1; k < 8; k++) ls += red8[row][k];
        mloc[((size_t)(s * B_) + b) * HM_ + row] = mg;
        lloc[((size_t)(s * B_) + b) * HM_ + row] = ls;
    }
    pT[j * 4 + 0][row] = e0; pT[j * 4 + 1][row] = e1;
    pT[j * 4 + 2][row] = e2; pT[j * 4 + 3][row] = e3;
    __syncthreads();

    // ---- phase 3: pax = p^T-weighted x. thread tile 8hm x 8c ----
    int cg = t & 63, hw = t >> 6;  // hw = wave = hm-group
    float o[8][8];
    #pragma unroll
    for (int i = 0; i < 8; i++)
        #pragma unroll
        for (int jj = 0; jj < 8; jj++) o[i][jj] = 0.f;
    const float* xb = &x[((size_t)(b * N_) + n0) * C_];
    #pragma unroll 4
    for (int n = 0; n < 32; n++) {
        float4 pa = *(float4*)&pT[n][hw * 8];
        float4 pb = *(float4*)&pT[n][hw * 8 + 4];
        float4 xa = *(const float4*)&xb[(size_t)n * C_ + cg * 4];
        float4 xc = *(const float4*)&xb[(size_t)n * C_ + 256 + cg * 4];
        float pv[8] = {pa.x, pa.y, pa.z, pa.w, pb.x, pb.y, pb.z, pb.w};
        #pragma unroll
        for (int i = 0; i < 8; i++) {
            o[i][0] += pv[i] * xa.x; o[i][1] += pv[i] * xa.y;
            o[i][2] += pv[i] * xa.z; o[i][3] += pv[i] * xa.w;
            o[i][4] += pv[i] * xc.x; o[i][5] += pv[i] * xc.y;
            o[i][6] += pv[i] * xc.z; o[i][7] += pv[i] * xc.w;
        }
    }
    #pragma unroll
    for (int i = 0; i < 8; i++) {
        int hm = hw * 8 + i;
        float* dst = &pax[(((size_t)(s * B_) + b) * HM_ + hm) * 512];
        *(float4*)&dst[cg * 4]       = make_float4(o[i][0], o[i][1], o[i][2], o[i][3]);
        *(float4*)&dst[256 + cg * 4] = make_float4(o[i][4], o[i][5], o[i][6], o[i][7]);
    }
}

// combine flash partials (scale by exp(m_loc - m_g)/l_g) then project with Wv.
// ov_part[cs][r][h*64+e] (no atomics)
__global__ __launch_bounds__(256) void k5a_ov(const float* __restrict__ Wkv, const float* __restrict__ pax,
                                              const float* __restrict__ mloc, const float* __restrict__ lloc,
                                              float* __restrict__ ov_part) {
    __shared__ float Wv[64][68];   // [cc][e]
    __shared__ float axh[16][68];  // [r][cc]
    __shared__ float sc[64][16];   // scale[s][r]
    __shared__ float redm[16][16];
    __shared__ float mgl[16], lgl[16];
    int t = threadIdx.x;
    int c0 = blockIdx.x * 64; int h = blockIdx.y;
    #pragma unroll
    for (int i = 0; i < 4; i++) {
        int f = t + i * 256; int cc = f >> 4, e4 = f & 15;
        *(float4*)&Wv[cc][e4 * 4] =
            *(const float4*)&Wkv[(size_t)(c0 + cc) * 1024 + 512 + h * 64 + e4 * 4];
    }
    // scale factors
    int r = t & 15, sg = t >> 4;   // 16 s-groups x 4 s
    int b = r >> 2, m = r & 3;
    float pm = -1e30f;
    #pragma unroll
    for (int k = 0; k < 4; k++) {
        int s = sg * 4 + k;
        pm = fmaxf(pm, mloc[((size_t)(s * B_) + b) * HM_ + h * M_ + m]);
    }
    redm[sg][r] = pm;
    __syncthreads();
    if (t < 16) {
        float mg = redm[0][t];
        #pragma unroll
        for (int k = 1; k < 16; k++) mg = fmaxf(mg, redm[k][t]);
        mgl[t] = mg;
    }
    __syncthreads();
    float mg = mgl[r];
    float pl = 0.f;
    #pragma unroll
    for (int k = 0; k < 4; k++) {
        int s = sg * 4 + k;
        float w = __expf(mloc[((size_t)(s * B_) + b) * HM_ + h * M_ + m] - mg);
        sc[s][r] = w;
        pl += w * lloc[((size_t)(s * B_) + b) * HM_ + h * M_ + m];
    }
    redm[sg][r] = pl;
    __syncthreads();
    if (t < 16) {
        float l = redm[0][t];
        #pragma unroll
        for (int k = 1; k < 16; k++) l += redm[k][t];
        lgl[t] = 1.0f / l;
    }
    __syncthreads();
    float inv = lgl[r];
    #pragma unroll
    for (int k = 0; k < 4; k++) sc[sg * 4 + k][r] *= inv;
    __syncthreads();
    // axh = sum_s scale * pax
    {
        int rr = t >> 4, c4 = t & 15;
        int bb = rr >> 2, mm = rr & 3;
        float4 a = make_float4(0.f, 0.f, 0.f, 0.f);
        for (int s = 0; s < 64; s++) {
            float w = sc[s][rr];
            float4 v = *(const float4*)&pax[(((size_t)(s * B_) + bb) * HM_ + h * M_ + mm) * 512 + c0 + c4 * 4];
            a.x += w * v.x; a.y += w * v.y; a.z += w * v.z; a.w += w * v.w;
        }
        *(float4*)&axh[rr][c4 * 4] = a;
    }
    __syncthreads();
    int e = t & 63, rg = t >> 6;
    float acc[4] = {0, 0, 0, 0};
    #pragma unroll 16
    for (int cc = 0; cc < 64; cc++) {
        float w = Wv[cc][e];
        #pragma unroll
        for (int i = 0; i < 4; i++) acc[i] += axh[rg * 4 + i][cc] * w;
    }
    #pragma unroll
    for (int i = 0; i < 4; i++) {
        int rr = rg * 4 + i;
        ov_part[((size_t)blockIdx.x * 16 + rr) * 512 + h * 64 + e] = acc[i];
    }
}

// out[r][j] = bo[j] + sum_i ov[r][i] * Wo[i][j];  ov = sum_cs ov_part. atomic over i-split.
__global__ __launch_bounds__(256) void k5b_out(const float* __restrict__ Wo, const float* __restrict__ bo,
                                               const float* __restrict__ ov_part, float* __restrict__ out) {
    __shared__ float W[64][68];
    __shared__ float ovr[16][68];
    int t = threadIdx.x;
    int i0 = blockIdx.x * 64; int j0 = blockIdx.y * 64;
    #pragma unroll
    for (int i = 0; i < 4; i++) {
        int f = t + i * 256; int ii = f >> 4, j4 = f & 15;
        *(float4*)&W[ii][j4 * 4] = *(const float4*)&Wo[(size_t)(i0 + ii) * 512 + j0 + j4 * 4];
    }
    {
        int r = t >> 4, c4 = t & 15;
        float4 a = make_float4(0.f, 0.f, 0.f, 0.f);
        #pragma unroll
        for (int cs = 0; cs < 8; cs++) {
            float4 v = *(const float4*)&ov_part[((size_t)cs * 16 + r) * 512 + i0 + c4 * 4];
            a.x += v.x; a.y += v.y; a.z += v.z; a.w += v.w;
        }
        *(float4*)&ovr[r][c4 * 4] = a;
    }
    __syncthreads();
    int j = t & 63, rg = t >> 6;
    float binit = (blockIdx.x == 0) ? bo[j0 + j] : 0.f;
    float acc[4] = {binit, binit, binit, binit};
    #pragma unroll 16
    for (int ii = 0; ii < 64; ii++) {
        float w = W[ii][j];
        #pragma unroll
        for (int i = 0; i < 4; i++) acc[i] += ovr[rg * 4 + i][ii] * w;
    }
    #pragma unroll
    for (int i = 0; i < 4; i++) {
        int r = rg * 4 + i;
        atomicAdd(&out[r * 512 + j0 + j], acc[i]);
    }
}

extern "C" void kernel_launch(void* const* d_in, const int* in_sizes, int n_in,
                              void* d_out, int out_size, void* d_ws, size_t ws_size,
                              hipStream_t stream) {
    const float* x    = (const float*)d_in[0];
    const float* bias = (const float*)d_in[1];
    const float* Wq   = (const float*)d_in[2];
    const float* Wkv  = (const float*)d_in[3];
    const float* Wo   = (const float*)d_in[4];
    const float* bo   = (const float*)d_in[5];
    float* out = (float*)d_out;
    float* ws  = (float*)d_ws;

    float* qk_ws   = ws + QK_OFF;
    float* pax     = ws + PAX_OFF;
    float* mloc    = ws + MLOC_OFF;
    float* lloc    = ws + LLOC_OFF;
    float* q_part  = ws + QP_OFF;
    float* ov_part = ws + OVP_OFF;

    k1a_q<<<dim3(8, 8), 256, 0, stream>>>(x, Wq, q_part);
    k1b_qk<<<dim3(8, 8), 256, 0, stream>>>(Wkv, q_part, qk_ws, out);
    k234_flash<<<dim3(S_, B_), 256, 0, stream>>>(x, qk_ws, bias, pax, mloc, lloc);
    k5a_ov<<<dim3(8, 8), 256, 0, stream>>>(Wkv, pax, mloc, lloc, ov_part);
    k5b_out<<<dim3(8, 8), 256, 0, stream>>>(Wo, bo, ov_part, out);
}